// Round 13
// baseline (1864.864 us; speedup 1.0000x reference)
//
#include <hip/hip_runtime.h>

#define NPTS 4096
#define NBATCH 16
#define THREADS 256
#define G 16
#define G3 (G * G * G)
#define LBOX 3.0f
#define H (6.0f / G)     // 0.375
#define INVH (G / 6.0f)

// Chamfer, fp32, B=16, N=M=4096, d=3 -- exact grid-pruned nearest neighbor.
// R8-R12: four structurally different all-pairs MFMA kernels all plateau at
// ~35us (10x pipe floor) -> the 537M-pair scan itself is the cost. Points are
// N(0,1)^3: a 16^3 grid (h=0.375) cuts expected candidates to ~130/query
// (ring 0+1), a 31x work reduction, EXACT via the ring lower bound:
// any point whose cell is at Chebyshev ring s from the query's cell lies at
// distance >= (s-1)*h - ov (ov = query overshoot outside its clamped cell;
// clamped targets overshoot only outward, never toward interior queries).
// Prep: 1 block/cloud: LDS histogram -> scan -> spatial sort + start|cnt<<16
// table; also zeroes out (no memset dispatch). Main: 1 query/thread in
// sorted order (wave-coherent cells -> L1 hits, low ring divergence).

__global__ __launch_bounds__(THREADS) void chamfer_prep(
    const float* __restrict__ shape, const float* __restrict__ tmpl,
    unsigned int* __restrict__ cellInfo, float4* __restrict__ ptsSorted,
    float* __restrict__ out) {
  __shared__ unsigned int hist[G3];    // 16 KB
  __shared__ unsigned int cursor[G3];  // 16 KB
  __shared__ unsigned int part[THREADS];

  const int cloud = blockIdx.x;  // src*16 + b
  const int src = cloud >> 4;
  const int b = cloud & 15;
  const float* P = (src == 0 ? shape : tmpl) + (size_t)b * NPTS * 3;
  const int tid = threadIdx.x;

  if (cloud == 0 && tid == 0) out[0] = 0.0f;  // poison-reset (main runs after)

  for (int i = tid; i < G3; i += THREADS) hist[i] = 0;
  __syncthreads();

  // Read 16 points/thread, compute cells, histogram.
  float px[16], py[16], pz[16];
  int pc[16];
  #pragma unroll
  for (int k = 0; k < 16; ++k) {
    const int i = tid + k * THREADS;
    const float x = P[3 * i + 0], y = P[3 * i + 1], z = P[3 * i + 2];
    px[k] = x; py[k] = y; pz[k] = z;
    const int cx = min(G - 1, max(0, (int)floorf((x + LBOX) * INVH)));
    const int cy = min(G - 1, max(0, (int)floorf((y + LBOX) * INVH)));
    const int cz = min(G - 1, max(0, (int)floorf((z + LBOX) * INVH)));
    pc[k] = (cz * G + cy) * G + cx;
    atomicAdd(&hist[pc[k]], 1u);
  }
  __syncthreads();

  // Exclusive scan over 4096 cells: 16 local + Hillis-Steele over 256 partials.
  unsigned int loc[16], sum = 0;
  #pragma unroll
  for (int i = 0; i < 16; ++i) { loc[i] = sum; sum += hist[tid * 16 + i]; }
  part[tid] = sum;
  __syncthreads();
  for (int off = 1; off < THREADS; off <<= 1) {
    const unsigned int v = (tid >= off) ? part[tid - off] : 0u;
    __syncthreads();
    part[tid] += v;
    __syncthreads();
  }
  const unsigned int excl = part[tid] - sum;
  #pragma unroll
  for (int i = 0; i < 16; ++i) {
    const int c = tid * 16 + i;
    const unsigned int st = excl + loc[i];
    cursor[c] = st;
    cellInfo[(size_t)cloud * G3 + c] = st | (hist[c] << 16);  // start|cnt
  }
  __syncthreads();

  // Scatter points into sorted order.
  #pragma unroll
  for (int k = 0; k < 16; ++k) {
    const unsigned int pos = atomicAdd(&cursor[pc[k]], 1u);
    ptsSorted[(size_t)cloud * NPTS + pos] = make_float4(px[k], py[k], pz[k], 0.0f);
  }
}

__global__ __launch_bounds__(THREADS) void chamfer_main(
    const unsigned int* __restrict__ cellInfo,
    const float4* __restrict__ ptsSorted, float* __restrict__ out) {
  __shared__ float redbuf[4];
  const int b = blockIdx.y;
  const int dir = blockIdx.z;
  const int qcloud = dir * NBATCH + b;        // dir0: queries = shape (src 0)
  const int tcloud = (1 - dir) * NBATCH + b;  // targets = the other cloud

  const float4 q =
      ptsSorted[(size_t)qcloud * NPTS + blockIdx.x * THREADS + threadIdx.x];
  const unsigned int* ci = cellInfo + (size_t)tcloud * G3;
  const float4* tp = ptsSorted + (size_t)tcloud * NPTS;

  const int cx = min(G - 1, max(0, (int)floorf((q.x + LBOX) * INVH)));
  const int cy = min(G - 1, max(0, (int)floorf((q.y + LBOX) * INVH)));
  const int cz = min(G - 1, max(0, (int)floorf((q.z + LBOX) * INVH)));
  // Overshoot of q outside its (clamped) cell box, Chebyshev.
  const float ox = fmaxf(0.0f, fmaxf((-LBOX + cx * H) - q.x, q.x - (-LBOX + (cx + 1) * H)));
  const float oy = fmaxf(0.0f, fmaxf((-LBOX + cy * H) - q.y, q.y - (-LBOX + (cy + 1) * H)));
  const float oz = fmaxf(0.0f, fmaxf((-LBOX + cz * H) - q.z, q.z - (-LBOX + (cz + 1) * H)));
  const float ov = fmaxf(ox, fmaxf(oy, oz));

  float best = 3.402823466e38f;
  for (int s = 0; s < G; ++s) {
    const float lb = (float)(s - 1) * H - ov;  // ring-s distance lower bound
    if (lb > 0.0f && lb * lb >= best) break;
    const int x0 = max(cx - s, 0), x1 = min(cx + s, G - 1);
    const int y0 = max(cy - s, 0), y1 = min(cy + s, G - 1);
    const int z0 = max(cz - s, 0), z1 = min(cz + s, G - 1);
    for (int zc = z0; zc <= z1; ++zc) {
      for (int yc = y0; yc <= y1; ++yc) {
        for (int xc = x0; xc <= x1; ++xc) {
          const int ring = max(abs(xc - cx), max(abs(yc - cy), abs(zc - cz)));
          if (ring != s) continue;  // only the shell (interior already done)
          const unsigned int info = ci[(zc * G + yc) * G + xc];
          const unsigned int st = info & 0xFFFFu;
          const unsigned int en = st + (info >> 16);
          for (unsigned int i = st; i < en; ++i) {
            const float4 t = tp[i];
            const float dx = q.x - t.x, dy = q.y - t.y, dz = q.z - t.z;
            best = fminf(best, fmaf(dx, dx, fmaf(dy, dy, dz * dz)));
          }
        }
      }
    }
  }

  float s1 = sqrtf(best);
  #pragma unroll
  for (int off = 32; off > 0; off >>= 1) s1 += __shfl_down(s1, off, 64);
  const int lane = threadIdx.x & 63;
  const int wid = threadIdx.x >> 6;
  if (lane == 0) redbuf[wid] = s1;
  __syncthreads();
  if (threadIdx.x == 0) {
    // out = 0.01 * mean over 16 batches of per-batch chamfer sums
    atomicAdd(out, (redbuf[0] + redbuf[1] + redbuf[2] + redbuf[3]) * (0.01f / 16.0f));
  }
}

// ---- Fallback (known-correct round-2 kernel) if ws is too small ----
__global__ __launch_bounds__(THREADS) void chamfer_fallback(
    const float* __restrict__ shape, const float* __restrict__ tmpl,
    float* __restrict__ out) {
  __shared__ float4 tile[NPTS];
  const int b = blockIdx.y;
  const int dir = blockIdx.z;
  const float* Pb = (dir == 0 ? shape : tmpl) + (size_t)b * NPTS * 3;
  const float* Tb = (dir == 0 ? tmpl : shape) + (size_t)b * NPTS * 3;
  const float4* T4 = (const float4*)Tb;
  for (int base = threadIdx.x * 4; base < NPTS; base += THREADS * 4) {
    const int k = base >> 2;
    float4 a = T4[3 * k + 0], c = T4[3 * k + 1], d = T4[3 * k + 2];
    tile[base + 0] = make_float4(a.x, a.y, a.z, 0.5f * fmaf(a.x, a.x, fmaf(a.y, a.y, a.z * a.z)));
    tile[base + 1] = make_float4(a.w, c.x, c.y, 0.5f * fmaf(a.w, a.w, fmaf(c.x, c.x, c.y * c.y)));
    tile[base + 2] = make_float4(c.z, c.w, d.x, 0.5f * fmaf(c.z, c.z, fmaf(c.w, c.w, d.x * d.x)));
    tile[base + 3] = make_float4(d.y, d.z, d.w, 0.5f * fmaf(d.y, d.y, fmaf(d.z, d.z, d.w * d.w)));
  }
  __syncthreads();
  const int m0 = blockIdx.x * (THREADS * 2) + threadIdx.x;
  const int m1 = m0 + THREADS;
  const float qx0 = Pb[3 * m0], qy0 = Pb[3 * m0 + 1], qz0 = Pb[3 * m0 + 2];
  const float qx1 = Pb[3 * m1], qy1 = Pb[3 * m1 + 1], qz1 = Pb[3 * m1 + 2];
  const float nx0 = -qx0, ny0 = -qy0, nz0 = -qz0;
  const float nx1 = -qx1, ny1 = -qy1, nz1 = -qz1;
  const float p20 = fmaf(qx0, qx0, fmaf(qy0, qy0, qz0 * qz0));
  const float p21 = fmaf(qx1, qx1, fmaf(qy1, qy1, qz1 * qz1));
  const float INF = 3.402823466e38f;
  float a00 = INF, a01 = INF, a10 = INF, a11 = INF;
  #pragma unroll 2
  for (int n = 0; n < NPTS; n += 2) {
    float4 t0 = tile[n], t1 = tile[n + 1];
    a00 = fminf(a00, fmaf(nx0, t0.x, fmaf(ny0, t0.y, fmaf(nz0, t0.z, t0.w))));
    a10 = fminf(a10, fmaf(nx1, t0.x, fmaf(ny1, t0.y, fmaf(nz1, t0.z, t0.w))));
    a01 = fminf(a01, fmaf(nx0, t1.x, fmaf(ny0, t1.y, fmaf(nz0, t1.z, t1.w))));
    a11 = fminf(a11, fmaf(nx1, t1.x, fmaf(ny1, t1.y, fmaf(nz1, t1.z, t1.w))));
  }
  float s = sqrtf(fmaxf(fmaf(2.0f, fminf(a00, a01), p20), 0.0f)) +
            sqrtf(fmaxf(fmaf(2.0f, fminf(a10, a11), p21), 0.0f));
  #pragma unroll
  for (int off = 32; off > 0; off >>= 1) s += __shfl_down(s, off, 64);
  __syncthreads();
  float* red = (float*)tile;
  if ((threadIdx.x & 63) == 0) red[threadIdx.x >> 6] = s;
  __syncthreads();
  if (threadIdx.x == 0)
    atomicAdd(out, (red[0] + red[1] + red[2] + red[3]) * (0.01f / 16.0f));
}

extern "C" void kernel_launch(void* const* d_in, const int* in_sizes, int n_in,
                              void* d_out, int out_size, void* d_ws, size_t ws_size,
                              hipStream_t stream) {
  const float* shape = (const float*)d_in[0];
  const float* tmpl = (const float*)d_in[1];
  float* out = (float*)d_out;

  const size_t info_bytes = (size_t)2 * NBATCH * G3 * sizeof(unsigned int);  // 512 KB
  const size_t pts_bytes = (size_t)2 * NBATCH * NPTS * sizeof(float4);       // 2 MB
  if (ws_size >= info_bytes + pts_bytes) {
    unsigned int* cellInfo = (unsigned int*)d_ws;
    float4* ptsSorted = (float4*)((char*)d_ws + info_bytes);  // 16B-aligned
    chamfer_prep<<<dim3(2 * NBATCH), dim3(THREADS), 0, stream>>>(
        shape, tmpl, cellInfo, ptsSorted, out);
    chamfer_main<<<dim3(NPTS / THREADS, NBATCH, 2), dim3(THREADS), 0, stream>>>(
        cellInfo, ptsSorted, out);
  } else {
    hipMemsetAsync(out, 0, sizeof(float) * out_size, stream);
    dim3 grid(NPTS / (THREADS * 2), NBATCH, 2);
    chamfer_fallback<<<grid, dim3(THREADS), 0, stream>>>(shape, tmpl, out);
  }
}

// Round 14
// 202.380 us; speedup vs baseline: 9.2146x; 9.2146x over previous
//
#include <hip/hip_runtime.h>

#define NPTS 4096
#define NBATCH 16
#define THREADS 256
#define G 16
#define G3 (G * G * G)
#define LBOX 3.0f
#define H (6.0f / G)     // 0.375
#define INVH (G / 6.0f)
#define MAXOVF (2 * NBATCH * NPTS)  // worst case: every query overflows

// Chamfer, fp32, B=16, N=M=4096, d=3 -- exact grid-pruned NN, straggler-free.
// R13's ring walk died on clamped outliers (ov large -> s~10, cube re-iter
// s^4 cells, 1.9ms stragglers at 2% occupancy). R14: bounded work per thread.
//  K2: scan exactly the 3x3x3 neighborhood (9 x-contiguous row spans, ~131
//      pts avg); exact finish test margin=H-ov>0 && margin^2>=best (ring>=2
//      targets are >= margin away; axis bound, clamped targets push outward).
//      Unfinished (~1-3%: outliers + sparse tails) -> overflow list (global
//      atomic), contribute 0 here.
//  K3: one wave per overflow entry: coalesced brute scan of all 4096 targets,
//      shuffle-min, sqrt, one atomicAdd. Exact for ANY distribution.
// Prep (verified R13, absmax 0.0): per-cloud histogram->scan->spatial sort +
// start|cnt<<16 cell table; zeroes out + overflow counter (no memset dispatch).

__global__ __launch_bounds__(THREADS) void chamfer_prep(
    const float* __restrict__ shape, const float* __restrict__ tmpl,
    unsigned int* __restrict__ cellInfo, float4* __restrict__ ptsSorted,
    unsigned int* __restrict__ ovfCount, float* __restrict__ out) {
  __shared__ unsigned int hist[G3];    // 16 KB
  __shared__ unsigned int cursor[G3];  // 16 KB
  __shared__ unsigned int part[THREADS];

  const int cloud = blockIdx.x;  // src*16 + b
  const int src = cloud >> 4;
  const int b = cloud & 15;
  const float* P = (src == 0 ? shape : tmpl) + (size_t)b * NPTS * 3;
  const int tid = threadIdx.x;

  if (cloud == 0 && tid == 0) {
    out[0] = 0.0f;     // d_out is 0xAA-poisoned; K2/K3 atomically accumulate
    *ovfCount = 0u;
  }

  for (int i = tid; i < G3; i += THREADS) hist[i] = 0;
  __syncthreads();

  float px[16], py[16], pz[16];
  int pc[16];
  #pragma unroll
  for (int k = 0; k < 16; ++k) {
    const int i = tid + k * THREADS;
    const float x = P[3 * i + 0], y = P[3 * i + 1], z = P[3 * i + 2];
    px[k] = x; py[k] = y; pz[k] = z;
    const int cx = min(G - 1, max(0, (int)floorf((x + LBOX) * INVH)));
    const int cy = min(G - 1, max(0, (int)floorf((y + LBOX) * INVH)));
    const int cz = min(G - 1, max(0, (int)floorf((z + LBOX) * INVH)));
    pc[k] = (cz * G + cy) * G + cx;
    atomicAdd(&hist[pc[k]], 1u);
  }
  __syncthreads();

  // Exclusive scan over 4096 cells: 16 local + Hillis-Steele over 256 partials.
  unsigned int loc[16], sum = 0;
  #pragma unroll
  for (int i = 0; i < 16; ++i) { loc[i] = sum; sum += hist[tid * 16 + i]; }
  part[tid] = sum;
  __syncthreads();
  for (int off = 1; off < THREADS; off <<= 1) {
    const unsigned int v = (tid >= off) ? part[tid - off] : 0u;
    __syncthreads();
    part[tid] += v;
    __syncthreads();
  }
  const unsigned int excl = part[tid] - sum;
  #pragma unroll
  for (int i = 0; i < 16; ++i) {
    const int c = tid * 16 + i;
    const unsigned int st = excl + loc[i];
    cursor[c] = st;
    cellInfo[(size_t)cloud * G3 + c] = st | (hist[c] << 16);  // start|cnt
  }
  __syncthreads();

  #pragma unroll
  for (int k = 0; k < 16; ++k) {
    const unsigned int pos = atomicAdd(&cursor[pc[k]], 1u);
    ptsSorted[(size_t)cloud * NPTS + pos] = make_float4(px[k], py[k], pz[k], 0.0f);
  }
}

__global__ __launch_bounds__(THREADS) void chamfer_main(
    const unsigned int* __restrict__ cellInfo,
    const float4* __restrict__ ptsSorted, unsigned int* __restrict__ ovfCount,
    float4* __restrict__ ovfList, float* __restrict__ out) {
  __shared__ float redbuf[4];
  const int b = blockIdx.y;
  const int dir = blockIdx.z;
  const int qcloud = dir * NBATCH + b;
  const int tcloud = (1 - dir) * NBATCH + b;

  const float4 q =
      ptsSorted[(size_t)qcloud * NPTS + blockIdx.x * THREADS + threadIdx.x];
  const unsigned int* ci = cellInfo + (size_t)tcloud * G3;
  const float4* tp = ptsSorted + (size_t)tcloud * NPTS;

  const int cx = min(G - 1, max(0, (int)floorf((q.x + LBOX) * INVH)));
  const int cy = min(G - 1, max(0, (int)floorf((q.y + LBOX) * INVH)));
  const int cz = min(G - 1, max(0, (int)floorf((q.z + LBOX) * INVH)));
  // Chebyshev overshoot of q outside its clamped cell box.
  const float ox = fmaxf(0.0f, fmaxf((-LBOX + cx * H) - q.x, q.x - (-LBOX + (cx + 1) * H)));
  const float oy = fmaxf(0.0f, fmaxf((-LBOX + cy * H) - q.y, q.y - (-LBOX + (cy + 1) * H)));
  const float oz = fmaxf(0.0f, fmaxf((-LBOX + cz * H) - q.z, q.z - (-LBOX + (cz + 1) * H)));
  const float ov = fmaxf(ox, fmaxf(oy, oz));

  // Bounded scan: 3x3x3 neighborhood as 9 x-contiguous row spans.
  float best = 3.402823466e38f;
  const int x0 = max(cx - 1, 0), x1 = min(cx + 1, G - 1);
  const int zlo = max(cz - 1, 0), zhi = min(cz + 1, G - 1);
  const int ylo = max(cy - 1, 0), yhi = min(cy + 1, G - 1);
  for (int zc = zlo; zc <= zhi; ++zc) {
    for (int yc = ylo; yc <= yhi; ++yc) {
      const int row = (zc * G + yc) * G;
      const unsigned int i0 = ci[row + x0];
      const unsigned int i1 = ci[row + x1];
      unsigned int i = i0 & 0xFFFFu;
      const unsigned int en = (i1 & 0xFFFFu) + (i1 >> 16);
      for (; i < en; ++i) {
        const float4 t = tp[i];
        const float dx = q.x - t.x, dy = q.y - t.y, dz = q.z - t.z;
        best = fminf(best, fmaf(dx, dx, fmaf(dy, dy, dz * dz)));
      }
    }
  }

  // Exact finish test: any ring>=2 target is >= (H - ov) away.
  const float margin = H - ov;
  const bool done = (margin > 0.0f) && (margin * margin >= best);
  float contrib = done ? sqrtf(best) : 0.0f;
  if (!done) {
    const unsigned int slot = atomicAdd(ovfCount, 1u);
    ovfList[slot] = make_float4(q.x, q.y, q.z, __int_as_float(tcloud));
  }

  #pragma unroll
  for (int off = 32; off > 0; off >>= 1)
    contrib += __shfl_down(contrib, off, 64);
  const int lane = threadIdx.x & 63;
  const int wid = threadIdx.x >> 6;
  if (lane == 0) redbuf[wid] = contrib;
  __syncthreads();
  if (threadIdx.x == 0)
    atomicAdd(out, (redbuf[0] + redbuf[1] + redbuf[2] + redbuf[3]) * (0.01f / 16.0f));
}

__global__ __launch_bounds__(THREADS) void chamfer_overflow(
    const float4* __restrict__ ptsSorted,
    const unsigned int* __restrict__ ovfCount,
    const float4* __restrict__ ovfList, float* __restrict__ out) {
  const unsigned int cnt = *ovfCount;
  const int lane = threadIdx.x & 63;
  const unsigned int waveId = (blockIdx.x * THREADS + threadIdx.x) >> 6;
  const unsigned int nWaves = (gridDim.x * THREADS) >> 6;

  for (unsigned int e = waveId; e < cnt; e += nWaves) {
    const float4 ent = ovfList[e];
    const int tc = __float_as_int(ent.w);
    const float4* tp = ptsSorted + (size_t)tc * NPTS;
    float best = 3.402823466e38f;
    // Coalesced brute scan: lane i covers points i, i+64, ...
    for (int i = lane; i < NPTS; i += 64) {
      const float4 t = tp[i];
      const float dx = ent.x - t.x, dy = ent.y - t.y, dz = ent.z - t.z;
      best = fminf(best, fmaf(dx, dx, fmaf(dy, dy, dz * dz)));
    }
    #pragma unroll
    for (int m = 1; m <= 32; m <<= 1)
      best = fminf(best, __shfl_xor(best, m, 64));
    if (lane == 0) atomicAdd(out, sqrtf(best) * (0.01f / 16.0f));
  }
}

// ---- Fallback (known-correct round-2 kernel) if ws is too small ----
__global__ __launch_bounds__(THREADS) void chamfer_fallback(
    const float* __restrict__ shape, const float* __restrict__ tmpl,
    float* __restrict__ out) {
  __shared__ float4 tile[NPTS];
  const int b = blockIdx.y;
  const int dir = blockIdx.z;
  const float* Pb = (dir == 0 ? shape : tmpl) + (size_t)b * NPTS * 3;
  const float* Tb = (dir == 0 ? tmpl : shape) + (size_t)b * NPTS * 3;
  const float4* T4 = (const float4*)Tb;
  for (int base = threadIdx.x * 4; base < NPTS; base += THREADS * 4) {
    const int k = base >> 2;
    float4 a = T4[3 * k + 0], c = T4[3 * k + 1], d = T4[3 * k + 2];
    tile[base + 0] = make_float4(a.x, a.y, a.z, 0.5f * fmaf(a.x, a.x, fmaf(a.y, a.y, a.z * a.z)));
    tile[base + 1] = make_float4(a.w, c.x, c.y, 0.5f * fmaf(a.w, a.w, fmaf(c.x, c.x, c.y * c.y)));
    tile[base + 2] = make_float4(c.z, c.w, d.x, 0.5f * fmaf(c.z, c.z, fmaf(c.w, c.w, d.x * d.x)));
    tile[base + 3] = make_float4(d.y, d.z, d.w, 0.5f * fmaf(d.y, d.y, fmaf(d.z, d.z, d.w * d.w)));
  }
  __syncthreads();
  const int m0 = blockIdx.x * (THREADS * 2) + threadIdx.x;
  const int m1 = m0 + THREADS;
  const float qx0 = Pb[3 * m0], qy0 = Pb[3 * m0 + 1], qz0 = Pb[3 * m0 + 2];
  const float qx1 = Pb[3 * m1], qy1 = Pb[3 * m1 + 1], qz1 = Pb[3 * m1 + 2];
  const float nx0 = -qx0, ny0 = -qy0, nz0 = -qz0;
  const float nx1 = -qx1, ny1 = -qy1, nz1 = -qz1;
  const float p20 = fmaf(qx0, qx0, fmaf(qy0, qy0, qz0 * qz0));
  const float p21 = fmaf(qx1, qx1, fmaf(qy1, qy1, qz1 * qz1));
  const float INF = 3.402823466e38f;
  float a00 = INF, a01 = INF, a10 = INF, a11 = INF;
  #pragma unroll 2
  for (int n = 0; n < NPTS; n += 2) {
    float4 t0 = tile[n], t1 = tile[n + 1];
    a00 = fminf(a00, fmaf(nx0, t0.x, fmaf(ny0, t0.y, fmaf(nz0, t0.z, t0.w))));
    a10 = fminf(a10, fmaf(nx1, t0.x, fmaf(ny1, t0.y, fmaf(nz1, t0.z, t0.w))));
    a01 = fminf(a01, fmaf(nx0, t1.x, fmaf(ny0, t1.y, fmaf(nz0, t1.z, t1.w))));
    a11 = fminf(a11, fmaf(nx1, t1.x, fmaf(ny1, t1.y, fmaf(nz1, t1.z, t1.w))));
  }
  float s = sqrtf(fmaxf(fmaf(2.0f, fminf(a00, a01), p20), 0.0f)) +
            sqrtf(fmaxf(fmaf(2.0f, fminf(a10, a11), p21), 0.0f));
  #pragma unroll
  for (int off = 32; off > 0; off >>= 1) s += __shfl_down(s, off, 64);
  __syncthreads();
  float* red = (float*)tile;
  if ((threadIdx.x & 63) == 0) red[threadIdx.x >> 6] = s;
  __syncthreads();
  if (threadIdx.x == 0)
    atomicAdd(out, (red[0] + red[1] + red[2] + red[3]) * (0.01f / 16.0f));
}

extern "C" void kernel_launch(void* const* d_in, const int* in_sizes, int n_in,
                              void* d_out, int out_size, void* d_ws, size_t ws_size,
                              hipStream_t stream) {
  const float* shape = (const float*)d_in[0];
  const float* tmpl = (const float*)d_in[1];
  float* out = (float*)d_out;

  const size_t info_bytes = (size_t)2 * NBATCH * G3 * sizeof(unsigned int);  // 512 KB
  const size_t pts_bytes = (size_t)2 * NBATCH * NPTS * sizeof(float4);       // 2 MB
  const size_t cnt_bytes = 16;  // counter, padded to 16B
  const size_t ovf_bytes = (size_t)MAXOVF * sizeof(float4);                  // 2 MB
  if (ws_size >= info_bytes + pts_bytes + cnt_bytes + ovf_bytes) {
    unsigned int* cellInfo = (unsigned int*)d_ws;
    float4* ptsSorted = (float4*)((char*)d_ws + info_bytes);
    unsigned int* ovfCount = (unsigned int*)((char*)d_ws + info_bytes + pts_bytes);
    float4* ovfList = (float4*)((char*)d_ws + info_bytes + pts_bytes + cnt_bytes);
    chamfer_prep<<<dim3(2 * NBATCH), dim3(THREADS), 0, stream>>>(
        shape, tmpl, cellInfo, ptsSorted, ovfCount, out);
    chamfer_main<<<dim3(NPTS / THREADS, NBATCH, 2), dim3(THREADS), 0, stream>>>(
        cellInfo, ptsSorted, ovfCount, ovfList, out);
    chamfer_overflow<<<dim3(256), dim3(THREADS), 0, stream>>>(
        ptsSorted, ovfCount, ovfList, out);
  } else {
    hipMemsetAsync(out, 0, sizeof(float) * out_size, stream);
    dim3 grid(NPTS / (THREADS * 2), NBATCH, 2);
    chamfer_fallback<<<grid, dim3(THREADS), 0, stream>>>(shape, tmpl, out);
  }
}

// Round 15
// 134.710 us; speedup vs baseline: 13.8435x; 1.5023x over previous
//
#include <hip/hip_runtime.h>

#define NPTS 4096
#define NBATCH 16
#define THREADS 256
#define G 16
#define G3 (G * G * G)
#define LBOX 3.0f
#define H (6.0f / G)     // 0.375
#define INVH (G / 6.0f)
#define MAXOVF (2 * NBATCH * NPTS)  // worst case: every query overflows

// Chamfer, fp32, B=16, N=M=4096, d=3 -- exact grid-pruned NN.
// R14: K2 (3x3x3 scan + exact margin test + overflow list) worked, but K3 did
// one contended atomicAdd(out) PER ENTRY (~5k serialized L2 RMWs -> 96us at
// 9.6% VALUBusy). R15: K3 = one BLOCK per entry (block-stride), coalesced
// scan, shuffle+LDS reduce, ONE atomic per block at exit (~1k uncontended).
//  margin bound: any target outside the 3x3x3 neighborhood is >= H - ov away
//  (ov = query's Chebyshev overshoot outside its clamped cell; clamped
//  targets only overshoot outward). done = margin>0 && margin^2 >= best.
// Prep (verified absmax 0.0): per-cloud histogram->scan->spatial sort +
// start|cnt<<16 cell table; zeroes out + ovfCount (no memset dispatch).

__global__ __launch_bounds__(THREADS) void chamfer_prep(
    const float* __restrict__ shape, const float* __restrict__ tmpl,
    unsigned int* __restrict__ cellInfo, float4* __restrict__ ptsSorted,
    unsigned int* __restrict__ ovfCount, float* __restrict__ out) {
  __shared__ unsigned int hist[G3];    // 16 KB
  __shared__ unsigned int cursor[G3];  // 16 KB
  __shared__ unsigned int part[THREADS];

  const int cloud = blockIdx.x;  // src*16 + b
  const int src = cloud >> 4;
  const int b = cloud & 15;
  const float* P = (src == 0 ? shape : tmpl) + (size_t)b * NPTS * 3;
  const int tid = threadIdx.x;

  if (cloud == 0 && tid == 0) {
    out[0] = 0.0f;     // d_out is 0xAA-poisoned; K2/K3 atomically accumulate
    *ovfCount = 0u;
  }

  for (int i = tid; i < G3; i += THREADS) hist[i] = 0;
  __syncthreads();

  float px[16], py[16], pz[16];
  int pc[16];
  #pragma unroll
  for (int k = 0; k < 16; ++k) {
    const int i = tid + k * THREADS;
    const float x = P[3 * i + 0], y = P[3 * i + 1], z = P[3 * i + 2];
    px[k] = x; py[k] = y; pz[k] = z;
    const int cx = min(G - 1, max(0, (int)floorf((x + LBOX) * INVH)));
    const int cy = min(G - 1, max(0, (int)floorf((y + LBOX) * INVH)));
    const int cz = min(G - 1, max(0, (int)floorf((z + LBOX) * INVH)));
    pc[k] = (cz * G + cy) * G + cx;
    atomicAdd(&hist[pc[k]], 1u);
  }
  __syncthreads();

  // Exclusive scan over 4096 cells: 16 local + Hillis-Steele over 256 partials.
  unsigned int loc[16], sum = 0;
  #pragma unroll
  for (int i = 0; i < 16; ++i) { loc[i] = sum; sum += hist[tid * 16 + i]; }
  part[tid] = sum;
  __syncthreads();
  for (int off = 1; off < THREADS; off <<= 1) {
    const unsigned int v = (tid >= off) ? part[tid - off] : 0u;
    __syncthreads();
    part[tid] += v;
    __syncthreads();
  }
  const unsigned int excl = part[tid] - sum;
  #pragma unroll
  for (int i = 0; i < 16; ++i) {
    const int c = tid * 16 + i;
    const unsigned int st = excl + loc[i];
    cursor[c] = st;
    cellInfo[(size_t)cloud * G3 + c] = st | (hist[c] << 16);  // start|cnt
  }
  __syncthreads();

  #pragma unroll
  for (int k = 0; k < 16; ++k) {
    const unsigned int pos = atomicAdd(&cursor[pc[k]], 1u);
    ptsSorted[(size_t)cloud * NPTS + pos] = make_float4(px[k], py[k], pz[k], 0.0f);
  }
}

__global__ __launch_bounds__(THREADS) void chamfer_main(
    const unsigned int* __restrict__ cellInfo,
    const float4* __restrict__ ptsSorted, unsigned int* __restrict__ ovfCount,
    float4* __restrict__ ovfList, float* __restrict__ out) {
  __shared__ float redbuf[4];
  const int b = blockIdx.y;
  const int dir = blockIdx.z;
  const int qcloud = dir * NBATCH + b;
  const int tcloud = (1 - dir) * NBATCH + b;

  const float4 q =
      ptsSorted[(size_t)qcloud * NPTS + blockIdx.x * THREADS + threadIdx.x];
  const unsigned int* ci = cellInfo + (size_t)tcloud * G3;
  const float4* tp = ptsSorted + (size_t)tcloud * NPTS;

  const int cx = min(G - 1, max(0, (int)floorf((q.x + LBOX) * INVH)));
  const int cy = min(G - 1, max(0, (int)floorf((q.y + LBOX) * INVH)));
  const int cz = min(G - 1, max(0, (int)floorf((q.z + LBOX) * INVH)));
  // Chebyshev overshoot of q outside its clamped cell box.
  const float ox = fmaxf(0.0f, fmaxf((-LBOX + cx * H) - q.x, q.x - (-LBOX + (cx + 1) * H)));
  const float oy = fmaxf(0.0f, fmaxf((-LBOX + cy * H) - q.y, q.y - (-LBOX + (cy + 1) * H)));
  const float oz = fmaxf(0.0f, fmaxf((-LBOX + cz * H) - q.z, q.z - (-LBOX + (cz + 1) * H)));
  const float ov = fmaxf(ox, fmaxf(oy, oz));

  // Bounded scan: 3x3x3 neighborhood as 9 x-contiguous row spans.
  float best = 3.402823466e38f;
  const int x0 = max(cx - 1, 0), x1 = min(cx + 1, G - 1);
  const int zlo = max(cz - 1, 0), zhi = min(cz + 1, G - 1);
  const int ylo = max(cy - 1, 0), yhi = min(cy + 1, G - 1);
  for (int zc = zlo; zc <= zhi; ++zc) {
    for (int yc = ylo; yc <= yhi; ++yc) {
      const int row = (zc * G + yc) * G;
      const unsigned int i0 = ci[row + x0];
      const unsigned int i1 = ci[row + x1];
      unsigned int i = i0 & 0xFFFFu;
      const unsigned int en = (i1 & 0xFFFFu) + (i1 >> 16);
      for (; i < en; ++i) {
        const float4 t = tp[i];
        const float dx = q.x - t.x, dy = q.y - t.y, dz = q.z - t.z;
        best = fminf(best, fmaf(dx, dx, fmaf(dy, dy, dz * dz)));
      }
    }
  }

  // Exact finish test: any target outside the neighborhood is >= H - ov away.
  const float margin = H - ov;
  const bool done = (margin > 0.0f) && (margin * margin >= best);
  float contrib = done ? sqrtf(best) : 0.0f;
  if (!done) {
    const unsigned int slot = atomicAdd(ovfCount, 1u);
    ovfList[slot] = make_float4(q.x, q.y, q.z, __int_as_float(tcloud));
  }

  #pragma unroll
  for (int off = 32; off > 0; off >>= 1)
    contrib += __shfl_down(contrib, off, 64);
  const int lane = threadIdx.x & 63;
  const int wid = threadIdx.x >> 6;
  if (lane == 0) redbuf[wid] = contrib;
  __syncthreads();
  if (threadIdx.x == 0)
    atomicAdd(out, (redbuf[0] + redbuf[1] + redbuf[2] + redbuf[3]) * (0.01f / 16.0f));
}

// One BLOCK per overflow entry (block-stride). Coalesced scan of all 4096
// targets (16 float4/thread), shuffle+LDS min-reduce, register-accumulated
// sum, ONE atomicAdd per block at exit (R14 did one per entry -> 96us).
__global__ __launch_bounds__(THREADS) void chamfer_overflow(
    const float4* __restrict__ ptsSorted,
    const unsigned int* __restrict__ ovfCount,
    const float4* __restrict__ ovfList, float* __restrict__ out) {
  __shared__ float wmin[4];
  const unsigned int cnt = *ovfCount;
  const int tid = threadIdx.x;
  const int lane = tid & 63;
  const int wid = tid >> 6;

  float bsum = 0.0f;  // thread 0's running sum over this block's entries
  for (unsigned int e = blockIdx.x; e < cnt; e += gridDim.x) {
    const float4 ent = ovfList[e];
    const int tc = __float_as_int(ent.w);
    const float4* tp = ptsSorted + (size_t)tc * NPTS;
    float best = 3.402823466e38f;
    #pragma unroll
    for (int k = 0; k < NPTS / THREADS; ++k) {
      const float4 t = tp[k * THREADS + tid];  // coalesced
      const float dx = ent.x - t.x, dy = ent.y - t.y, dz = ent.z - t.z;
      best = fminf(best, fmaf(dx, dx, fmaf(dy, dy, dz * dz)));
    }
    #pragma unroll
    for (int m = 1; m <= 32; m <<= 1)
      best = fminf(best, __shfl_xor(best, m, 64));
    __syncthreads();  // wmin free from previous entry
    if (lane == 0) wmin[wid] = best;
    __syncthreads();
    if (tid == 0)
      bsum += sqrtf(fminf(fminf(wmin[0], wmin[1]), fminf(wmin[2], wmin[3])));
  }
  if (tid == 0 && bsum != 0.0f)
    atomicAdd(out, bsum * (0.01f / 16.0f));
}

// ---- Fallback (known-correct round-2 kernel) if ws is too small ----
__global__ __launch_bounds__(THREADS) void chamfer_fallback(
    const float* __restrict__ shape, const float* __restrict__ tmpl,
    float* __restrict__ out) {
  __shared__ float4 tile[NPTS];
  const int b = blockIdx.y;
  const int dir = blockIdx.z;
  const float* Pb = (dir == 0 ? shape : tmpl) + (size_t)b * NPTS * 3;
  const float* Tb = (dir == 0 ? tmpl : shape) + (size_t)b * NPTS * 3;
  const float4* T4 = (const float4*)Tb;
  for (int base = threadIdx.x * 4; base < NPTS; base += THREADS * 4) {
    const int k = base >> 2;
    float4 a = T4[3 * k + 0], c = T4[3 * k + 1], d = T4[3 * k + 2];
    tile[base + 0] = make_float4(a.x, a.y, a.z, 0.5f * fmaf(a.x, a.x, fmaf(a.y, a.y, a.z * a.z)));
    tile[base + 1] = make_float4(a.w, c.x, c.y, 0.5f * fmaf(a.w, a.w, fmaf(c.x, c.x, c.y * c.y)));
    tile[base + 2] = make_float4(c.z, c.w, d.x, 0.5f * fmaf(c.z, c.z, fmaf(c.w, c.w, d.x * d.x)));
    tile[base + 3] = make_float4(d.y, d.z, d.w, 0.5f * fmaf(d.y, d.y, fmaf(d.z, d.z, d.w * d.w)));
  }
  __syncthreads();
  const int m0 = blockIdx.x * (THREADS * 2) + threadIdx.x;
  const int m1 = m0 + THREADS;
  const float qx0 = Pb[3 * m0], qy0 = Pb[3 * m0 + 1], qz0 = Pb[3 * m0 + 2];
  const float qx1 = Pb[3 * m1], qy1 = Pb[3 * m1 + 1], qz1 = Pb[3 * m1 + 2];
  const float nx0 = -qx0, ny0 = -qy0, nz0 = -qz0;
  const float nx1 = -qx1, ny1 = -qy1, nz1 = -qz1;
  const float p20 = fmaf(qx0, qx0, fmaf(qy0, qy0, qz0 * qz0));
  const float p21 = fmaf(qx1, qx1, fmaf(qy1, qy1, qz1 * qz1));
  const float INF = 3.402823466e38f;
  float a00 = INF, a01 = INF, a10 = INF, a11 = INF;
  #pragma unroll 2
  for (int n = 0; n < NPTS; n += 2) {
    float4 t0 = tile[n], t1 = tile[n + 1];
    a00 = fminf(a00, fmaf(nx0, t0.x, fmaf(ny0, t0.y, fmaf(nz0, t0.z, t0.w))));
    a10 = fminf(a10, fmaf(nx1, t0.x, fmaf(ny1, t0.y, fmaf(nz1, t0.z, t0.w))));
    a01 = fminf(a01, fmaf(nx0, t1.x, fmaf(ny0, t1.y, fmaf(nz0, t1.z, t1.w))));
    a11 = fminf(a11, fmaf(nx1, t1.x, fmaf(ny1, t1.y, fmaf(nz1, t1.z, t1.w))));
  }
  float s = sqrtf(fmaxf(fmaf(2.0f, fminf(a00, a01), p20), 0.0f)) +
            sqrtf(fmaxf(fmaf(2.0f, fminf(a10, a11), p21), 0.0f));
  #pragma unroll
  for (int off = 32; off > 0; off >>= 1) s += __shfl_down(s, off, 64);
  __syncthreads();
  float* red = (float*)tile;
  if ((threadIdx.x & 63) == 0) red[threadIdx.x >> 6] = s;
  __syncthreads();
  if (threadIdx.x == 0)
    atomicAdd(out, (red[0] + red[1] + red[2] + red[3]) * (0.01f / 16.0f));
}

extern "C" void kernel_launch(void* const* d_in, const int* in_sizes, int n_in,
                              void* d_out, int out_size, void* d_ws, size_t ws_size,
                              hipStream_t stream) {
  const float* shape = (const float*)d_in[0];
  const float* tmpl = (const float*)d_in[1];
  float* out = (float*)d_out;

  const size_t info_bytes = (size_t)2 * NBATCH * G3 * sizeof(unsigned int);  // 512 KB
  const size_t pts_bytes = (size_t)2 * NBATCH * NPTS * sizeof(float4);       // 2 MB
  const size_t cnt_bytes = 16;
  const size_t ovf_bytes = (size_t)MAXOVF * sizeof(float4);                  // 2 MB
  if (ws_size >= info_bytes + pts_bytes + cnt_bytes + ovf_bytes) {
    unsigned int* cellInfo = (unsigned int*)d_ws;
    float4* ptsSorted = (float4*)((char*)d_ws + info_bytes);
    unsigned int* ovfCount = (unsigned int*)((char*)d_ws + info_bytes + pts_bytes);
    float4* ovfList = (float4*)((char*)d_ws + info_bytes + pts_bytes + cnt_bytes);
    chamfer_prep<<<dim3(2 * NBATCH), dim3(THREADS), 0, stream>>>(
        shape, tmpl, cellInfo, ptsSorted, ovfCount, out);
    chamfer_main<<<dim3(NPTS / THREADS, NBATCH, 2), dim3(THREADS), 0, stream>>>(
        cellInfo, ptsSorted, ovfCount, ovfList, out);
    chamfer_overflow<<<dim3(1024), dim3(THREADS), 0, stream>>>(
        ptsSorted, ovfCount, ovfList, out);
  } else {
    hipMemsetAsync(out, 0, sizeof(float) * out_size, stream);
    dim3 grid(NPTS / (THREADS * 2), NBATCH, 2);
    chamfer_fallback<<<grid, dim3(THREADS), 0, stream>>>(shape, tmpl, out);
  }
}